// Round 1
// baseline (2906.569 us; speedup 1.0000x reference)
//
#include <hip/hip_runtime.h>

// ---------------- sizes / workspace layout (floats) ----------------
constexpr int BB   = 16;
constexpr int VS   = BB*3*32*32;     // 49152
constexpr int M1N  = BB*64*32*32;    // 1048576
constexpr int O1PN = BB*64*18*20;    // 368640 (padded 16x16 interior)
constexpr int M2N  = BB*128*16*16;   // 524288
constexpr int O2PN = BB*128*18*20;   // 737280
constexpr int M3N  = M2N;
constexpr int FBN  = BB*8192;        // 131072
constexpr int M4N  = BB*1024;
constexpr int M5N  = BB*1024;

constexpr int off_v   = 0;                 // x2 ping-pong
constexpr int off_s   = off_v   + 2*VS;
constexpr int off_m1  = off_s   + 2*VS;
constexpr int off_o1p = off_m1  + M1N;     // x2
constexpr int off_m2  = off_o1p + 2*O1PN;
constexpr int off_o2p = off_m2  + M2N;     // x2
constexpr int off_m3  = off_o2p + 2*O2PN;
constexpr int off_f   = off_m3  + M3N;     // x2
constexpr int off_m4  = off_f   + 2*FBN;
constexpr int off_o4  = off_m4  + M4N;     // x2
constexpr int off_m5  = off_o4  + 2*M4N;
constexpr int off_o5  = off_m5  + M5N;     // x2
constexpr int off_w1r = off_o5  + 2*M5N;   // zero-region ends here
constexpr int W1RN = 64*3*12;
constexpr int off_w2r = off_w1r + W1RN;
constexpr int W2RN = 128*64*12;
constexpr int off_w3r = off_w2r + W2RN;
constexpr int W3RN = 128*128*12;
constexpr int TOTF = off_w3r + W3RN;       // ~5.16M floats (~20.7 MB)
constexpr int ZTOT = off_w1r;

__device__ __forceinline__ float4 ld4(const float* p){ return *reinterpret_cast<const float4*>(p); }
__device__ __forceinline__ float2 ld2(const float* p){ return *reinterpret_cast<const float2*>(p); }
__device__ __forceinline__ float spk(float m){ return m > 1.0f ? 1.0f : 0.0f; }

// ---------------- init: zero state, repack conv weights to [co][ci][12] ----------------
__global__ __launch_bounds__(256) void init_k(const float* __restrict__ W1,
                                              const float* __restrict__ W2,
                                              const float* __restrict__ W3,
                                              float* __restrict__ ws,
                                              float* __restrict__ out) {
    int i0 = blockIdx.x*256 + threadIdx.x;
    int stride = gridDim.x*256;
    for (int p = i0; p < TOTF; p += stride) {
        float val = 0.0f;
        if (p >= off_w1r) {
            int q, r; const float* src;
            if (p < off_w2r)      { int l = p - off_w1r; q = l/12; r = l%12; src = W1; }
            else if (p < off_w3r) { int l = p - off_w2r; q = l/12; r = l%12; src = W2; }
            else                  { int l = p - off_w3r; q = l/12; r = l%12; src = W3; }
            int dx = r & 3, dy = r >> 2;
            val = (dx < 3) ? src[q*9 + dy*3 + dx] : 0.0f;
        }
        ws[p] = val;
    }
    if (i0 < 160) out[i0] = 0.0f;
}

// ---------------- one fused timestep ----------------
__global__ __launch_bounds__(256) void step_k(const float* __restrict__ x,
                                              const float* __restrict__ L1,
                                              const float* __restrict__ L2,
                                              const float* __restrict__ L3,
                                              float* __restrict__ ws,
                                              float* __restrict__ out,
                                              int t) {
    const int rp = t & 1, wp = rp ^ 1;
    const int bid = blockIdx.x, tid = threadIdx.x;
    __shared__ float shbuf[256*17];   // fc reduction; role A uses first 360

    if (bid < 256) {
        // ---- Role A: encoder (redundant) + conv1 + LIF(m1) + write pooled next-spike ----
        int b = bid >> 4, tile = bid & 15;
        int ty = tile >> 2, tx = tile & 3;
        int y0 = ty*8, x0 = tx*8;
        const float* vin  = ws + off_v + rp*VS + b*3072;
        float*       vout = ws + off_v + wp*VS + b*3072;
        const float* sin_ = ws + off_s + rp*VS + b*3072;
        float*       sout = ws + off_s + wp*VS + b*3072;
        const float* xin  = x + b*3072;
        float* sl = shbuf; // [3][10][12]
        for (int idx = tid; idx < 300; idx += 256) {
            int ci = idx/100, r2 = idx%100, rr = r2/10, cc = r2%10;
            int yy = y0 - 1 + rr, xx = x0 - 1 + cc;
            float sv = 0.0f;
            if ((unsigned)yy < 32u && (unsigned)xx < 32u) {
                int g = ci*1024 + yy*32 + xx;
                float vn = vin[g] + xin[g] - sin_[g];
                sv = vn > 1.0f ? 1.0f : 0.0f;
                if (yy >= y0 && yy < y0+8 && xx >= x0 && xx < x0+8) { vout[g] = vn; sout[g] = sv; }
            }
            sl[(ci*10 + rr)*12 + cc] = sv;
        }
        __syncthreads();
        int tl = tid & 15, cog = tid >> 4;
        int py = (tl >> 2)*2, px = (tl & 3)*2;
        for (int cl = 0; cl < 4; ++cl) {
            int co = cog*4 + cl;
            const float* wtp = ws + off_w1r + co*36;
            float a00=0,a01=0,a10=0,a11=0;
            #pragma unroll
            for (int ci = 0; ci < 3; ++ci) {
                float4 w0 = ld4(wtp + ci*12), w1 = ld4(wtp + ci*12 + 4), w2 = ld4(wtp + ci*12 + 8);
                float wd[3][3] = {{w0.x,w0.y,w0.z},{w1.x,w1.y,w1.z},{w2.x,w2.y,w2.z}};
                #pragma unroll
                for (int dy = 0; dy < 3; ++dy)
                    #pragma unroll
                    for (int dx = 0; dx < 3; ++dx) {
                        float wv = wd[dy][dx];
                        const float* rsl = sl + (ci*10 + py + dy)*12 + px + dx;
                        a00 += rsl[0]  * wv; a01 += rsl[1]  * wv;
                        a10 += rsl[12] * wv; a11 += rsl[13] * wv;
                    }
            }
            int gy = y0 + py, gx = x0 + px;
            float accs[2][2] = {{a00,a01},{a10,a11}};
            float pooled = 0.0f;
            #pragma unroll
            for (int iy = 0; iy < 2; ++iy)
                #pragma unroll
                for (int ix = 0; ix < 2; ++ix) {
                    int gm = off_m1 + ((b*64 + co)*32 + gy + iy)*32 + gx + ix;
                    float m = ws[gm], o = spk(m);
                    float mn = m + accs[iy][ix] - o;
                    ws[gm] = mn;
                    pooled += spk(mn);
                }
            ws[off_o1p + wp*O1PN + ((b*64 + co)*18 + (gy>>1) + 1)*20 + (gx>>1) + 1] = pooled*0.25f;
        }
    } else if (bid < 512) {
        // ---- Role B: conv2 (64->128, 16x16) + LIF(m2) + write padded next-spike ----
        int bb2 = bid - 256, b = bb2 >> 4, cog = bb2 & 15;
        int cl = tid >> 5, rest = tid & 31, y = rest >> 1, x0 = (rest & 1)*8;
        int co = cog*8 + cl;
        const float* ip = ws + off_o1p + rp*O1PN + b*64*360;
        const float* wt = ws + off_w2r + co*768;
        float acc[8] = {0,0,0,0,0,0,0,0};
        for (int ci = 0; ci < 64; ++ci) {
            float4 w0 = ld4(wt + ci*12), w1 = ld4(wt + ci*12 + 4), w2 = ld4(wt + ci*12 + 8);
            float wd[3][3] = {{w0.x,w0.y,w0.z},{w1.x,w1.y,w1.z},{w2.x,w2.y,w2.z}};
            const float* rbase = ip + ci*360 + y*20 + x0;
            #pragma unroll
            for (int dy = 0; dy < 3; ++dy) {
                float4 u0 = ld4(rbase + dy*20);
                float4 u1 = ld4(rbase + dy*20 + 4);
                float2 u2 = ld2(rbase + dy*20 + 8);
                float rv[10] = {u0.x,u0.y,u0.z,u0.w,u1.x,u1.y,u1.z,u1.w,u2.x,u2.y};
                #pragma unroll
                for (int dx = 0; dx < 3; ++dx) {
                    float wv = wd[dy][dx];
                    #pragma unroll
                    for (int p = 0; p < 8; ++p) acc[p] += rv[p+dx]*wv;
                }
            }
        }
        int mbase = off_m2 + ((b*128 + co)*16 + y)*16 + x0;
        int obase = off_o2p + wp*O2PN + ((b*128 + co)*18 + y + 1)*20 + x0 + 1;
        #pragma unroll
        for (int p = 0; p < 8; ++p) {
            float m = ws[mbase+p], o = spk(m);
            float mn = m + acc[p] - o;
            ws[mbase+p] = mn;
            ws[obase+p] = spk(mn);
        }
    } else if (bid < 768) {
        // ---- Role C: conv3 (128->128, 16x16) + LIF(m3) + pool -> fbuf next ----
        int bb3 = bid - 512, b = bb3 >> 4, cog = bb3 & 15;
        int cl = tid >> 5, rest = tid & 31, rpair = rest >> 2, cg = rest & 3;
        int y0 = rpair*2, x0 = cg*4;
        int co = cog*8 + cl;
        const float* ip = ws + off_o2p + rp*O2PN + b*128*360;
        const float* wt = ws + off_w3r + co*1536;
        float acc[2][4] = {{0,0,0,0},{0,0,0,0}};
        for (int ci = 0; ci < 128; ++ci) {
            float4 w0 = ld4(wt + ci*12), w1 = ld4(wt + ci*12 + 4), w2 = ld4(wt + ci*12 + 8);
            float wd[3][3] = {{w0.x,w0.y,w0.z},{w1.x,w1.y,w1.z},{w2.x,w2.y,w2.z}};
            const float* rbase = ip + ci*360 + y0*20 + x0;
            float rv[4][6];
            #pragma unroll
            for (int r = 0; r < 4; ++r) {
                float4 u0 = ld4(rbase + r*20);
                float2 u1 = ld2(rbase + r*20 + 4);
                rv[r][0]=u0.x; rv[r][1]=u0.y; rv[r][2]=u0.z; rv[r][3]=u0.w; rv[r][4]=u1.x; rv[r][5]=u1.y;
            }
            #pragma unroll
            for (int iy = 0; iy < 2; ++iy)
                #pragma unroll
                for (int dy = 0; dy < 3; ++dy) {
                    int r = iy + dy;
                    #pragma unroll
                    for (int dx = 0; dx < 3; ++dx) {
                        float wv = wd[dy][dx];
                        #pragma unroll
                        for (int p = 0; p < 4; ++p) acc[iy][p] += rv[r][p+dx]*wv;
                    }
                }
        }
        float sp[2][4];
        #pragma unroll
        for (int iy = 0; iy < 2; ++iy)
            #pragma unroll
            for (int p = 0; p < 4; ++p) {
                int gm = off_m3 + ((b*128 + co)*16 + y0 + iy)*16 + x0 + p;
                float m = ws[gm], o = spk(m);
                float mn = m + acc[iy][p] - o;
                ws[gm] = mn;
                sp[iy][p] = spk(mn);
            }
        int fbase = off_f + wp*FBN + b*8192 + co*64 + (y0>>1)*8 + (x0>>1);
        ws[fbase+0] = (sp[0][0]+sp[0][1]+sp[1][0]+sp[1][1])*0.25f;
        ws[fbase+1] = (sp[0][2]+sp[0][3]+sp[1][2]+sp[1][3])*0.25f;
    } else if (bid < 832) {
        // ---- Role D: fc1 8192->1024 + LIF(m4) ----
        int jb = bid - 768;                       // 16 cols per block
        int jg = tid >> 6, bg = (tid >> 4) & 3, ks = tid & 15;
        int j0 = jb*16 + jg*4, b0 = bg*4;
        const float* fp = ws + off_f + rp*FBN;
        float acc[4][4] = {};
        for (int i = 0; i < 128; ++i) {           // lane-interleaved K for coalescing
            int k = i*64 + ks*4;
            float4 wv[4], fv[4];
            #pragma unroll
            for (int jj = 0; jj < 4; ++jj) wv[jj] = ld4(L1 + (j0+jj)*8192 + k);
            #pragma unroll
            for (int bb = 0; bb < 4; ++bb) fv[bb] = ld4(fp + (b0+bb)*8192 + k);
            #pragma unroll
            for (int jj = 0; jj < 4; ++jj)
                #pragma unroll
                for (int bb = 0; bb < 4; ++bb)
                    acc[jj][bb] += wv[jj].x*fv[bb].x + wv[jj].y*fv[bb].y +
                                   wv[jj].z*fv[bb].z + wv[jj].w*fv[bb].w;
        }
        #pragma unroll
        for (int jj = 0; jj < 4; ++jj)
            #pragma unroll
            for (int bb = 0; bb < 4; ++bb) shbuf[tid*17 + jj*4 + bb] = acc[jj][bb];
        __syncthreads();
        int jl = tid >> 4, bo = tid & 15;
        int tbase = (jl >> 2)*64 + (bo >> 2)*16;
        int slot  = (jl & 3)*4 + (bo & 3);
        float sum = 0.0f;
        #pragma unroll
        for (int k2 = 0; k2 < 16; ++k2) sum += shbuf[(tbase + k2)*17 + slot];
        int j = jb*16 + jl;
        int gi = off_m4 + bo*1024 + j;
        float m = ws[gi], o = spk(m);
        float mn = m + sum - o;
        ws[gi] = mn;
        ws[off_o4 + wp*M4N + bo*1024 + j] = spk(mn);
    } else if (bid < 864) {
        // ---- Role E: fc2 1024->1024 + LIF(m5) ----
        int jb = bid - 832;                       // 32 cols per block
        int jg = tid >> 5, bg = (tid >> 3) & 3, ks = tid & 7;
        int j0 = jb*32 + jg*4, b0 = bg*4;
        const float* op = ws + off_o4 + rp*M4N;
        float acc[4][4] = {};
        for (int i = 0; i < 32; ++i) {
            int k = i*32 + ks*4;
            float4 wv[4], fv[4];
            #pragma unroll
            for (int jj = 0; jj < 4; ++jj) wv[jj] = ld4(L2 + (j0+jj)*1024 + k);
            #pragma unroll
            for (int bb = 0; bb < 4; ++bb) fv[bb] = ld4(op + (b0+bb)*1024 + k);
            #pragma unroll
            for (int jj = 0; jj < 4; ++jj)
                #pragma unroll
                for (int bb = 0; bb < 4; ++bb)
                    acc[jj][bb] += wv[jj].x*fv[bb].x + wv[jj].y*fv[bb].y +
                                   wv[jj].z*fv[bb].z + wv[jj].w*fv[bb].w;
        }
        #pragma unroll
        for (int jj = 0; jj < 4; ++jj)
            #pragma unroll
            for (int bb = 0; bb < 4; ++bb) shbuf[tid*17 + jj*4 + bb] = acc[jj][bb];
        __syncthreads();
        for (int rep = 0; rep < 2; ++rep) {
            int oid = rep*256 + tid;
            int jl = oid >> 4, bo = oid & 15;
            int tbase = (jl >> 2)*32 + (bo >> 2)*8;
            int slot  = (jl & 3)*4 + (bo & 3);
            float sum = 0.0f;
            #pragma unroll
            for (int k2 = 0; k2 < 8; ++k2) sum += shbuf[(tbase + k2)*17 + slot];
            int j = jb*32 + jl;
            int gi = off_m5 + bo*1024 + j;
            float m = ws[gi], o = spk(m);
            float mn = m + sum - o;
            ws[gi] = mn;
            ws[off_o5 + wp*M5N + bo*1024 + j] = spk(mn);
        }
    } else {
        // ---- Role F: fc3 1024->10, accumulate output membrane ----
        if (tid < 160) {
            int b = tid/10, c = tid - b*10;
            const float* op = ws + off_o5 + rp*M5N + b*1024;
            const float* wr = L3 + c*1024;
            float sum = 0.0f;
            for (int k = 0; k < 1024; k += 4) {
                float4 a = ld4(op + k), wv = ld4(wr + k);
                sum += a.x*wv.x + a.y*wv.y + a.z*wv.z + a.w*wv.w;
            }
            out[b*10 + c] += sum;
        }
    }
}

extern "C" void kernel_launch(void* const* d_in, const int* in_sizes, int n_in,
                              void* d_out, int out_size, void* d_ws, size_t ws_size,
                              hipStream_t stream) {
    const float* x  = (const float*)d_in[0];
    const float* W1 = (const float*)d_in[1];
    const float* W2 = (const float*)d_in[2];
    const float* W3 = (const float*)d_in[3];
    const float* L1 = (const float*)d_in[4];
    const float* L2 = (const float*)d_in[5];
    const float* L3 = (const float*)d_in[6];
    float* out = (float*)d_out;
    float* ws  = (float*)d_ws;

    init_k<<<1024, 256, 0, stream>>>(W1, W2, W3, ws, out);
    for (int t = 0; t < 20; ++t)
        step_k<<<865, 256, 0, stream>>>(x, L1, L2, L3, ws, out, t);
}